// Round 1
// baseline (4092.678 us; speedup 1.0000x reference)
//
#include <hip/hip_runtime.h>
#include <hip/hip_bf16.h>
#include <cstdint>
#include <cstddef>

#define DEV __device__ __forceinline__

constexpr int Bb = 2, Ls = 4096, Dd = 2048, Hh = 32, HD = 64, MBK = 16, NMBc = 256;
constexpr int MTOK = Bb * Ls; // 8192 tokens

typedef __bf16 bf16x8 __attribute__((ext_vector_type(8)));
typedef float  f32x4  __attribute__((ext_vector_type(4)));

DEV unsigned short f2bf(float f) {
    union { float f; unsigned int u; } x; x.f = f;
    unsigned int u = x.u;
    return (unsigned short)((u + 0x7fffu + ((u >> 16) & 1u)) >> 16);
}

DEV float wsum64(float v) {
    #pragma unroll
    for (int m = 32; m >= 1; m >>= 1) v += __shfl_xor(v, m, 64);
    return v;
}

DEV void g2l16(const void* g, void* l) {
    __builtin_amdgcn_global_load_lds(
        (__attribute__((address_space(1))) void*)(g),
        (__attribute__((address_space(3))) void*)(l), 16, 0, 0);
}

// ---------------- cast hidden_states fp32 -> bf16 ----------------
__global__ __launch_bounds__(256) void cast_hs_kernel(const float* __restrict__ src,
                                                      unsigned short* __restrict__ dst) {
    int i = (blockIdx.x * 256 + threadIdx.x) * 4;
    float4 v = *(const float4*)(src + i);
    ushort4 o; o.x = f2bf(v.x); o.y = f2bf(v.y); o.z = f2bf(v.z); o.w = f2bf(v.w);
    *(ushort4*)(dst + i) = o;
}

// ---------------- transpose + cast weight: W[k][n] fp32 -> Wt[n][k] bf16 ----------------
__global__ __launch_bounds__(256) void transpose_cast_kernel(const float* __restrict__ W,
                                                             unsigned short* __restrict__ Wt) {
    __shared__ float tile[64][65];
    int bx = blockIdx.x & 31;   // k-tile
    int by = blockIdx.x >> 5;   // n-tile
    int t = threadIdx.x;
    int r = t >> 4, c4 = (t & 15) * 4;
    #pragma unroll
    for (int i = 0; i < 4; ++i) {
        int row = r + i * 16;
        float4 v = *(const float4*)(W + (size_t)(bx * 64 + row) * Dd + by * 64 + c4);
        tile[row][c4 + 0] = v.x; tile[row][c4 + 1] = v.y;
        tile[row][c4 + 2] = v.z; tile[row][c4 + 3] = v.w;
    }
    __syncthreads();
    #pragma unroll
    for (int i = 0; i < 4; ++i) {
        int row = r + i * 16; // n index
        ushort4 o;
        o.x = f2bf(tile[c4 + 0][row]); o.y = f2bf(tile[c4 + 1][row]);
        o.z = f2bf(tile[c4 + 2][row]); o.w = f2bf(tile[c4 + 3][row]);
        *(ushort4*)(Wt + (size_t)(by * 64 + row) * Dd + bx * 64 + c4) = o;
    }
}

// ---------------- bf16 MFMA GEMM:  C[M,N] = A[M,K] @ Bt[N,K]^T + bias ----------------
// 128x128 tile, BK=64, XOR-swizzled LDS (blk ^ (row&7)) so global_load_lds (lane*16 dst)
// and conflict-free ds_read_b128 coexist without padding.
__global__ __launch_bounds__(256) void gemm_bt_kernel(const unsigned short* __restrict__ A,
                                                      const unsigned short* __restrict__ Bt,
                                                      const float* __restrict__ bias,
                                                      float* __restrict__ C,
                                                      int M, int N, int Kd) {
    __shared__ unsigned short sA[128 * 64];
    __shared__ unsigned short sB[128 * 64];
    int t = threadIdx.x;
    int lane = t & 63;
    int wid = t >> 6, wm = wid >> 1, wn = wid & 1;
    int quad = lane >> 4, c = lane & 15;
    int bm = blockIdx.x, bn = blockIdx.y;

    // staging pointers
    const unsigned short* pa[4]; const unsigned short* pb[4];
    unsigned short* la[4]; unsigned short* lb[4];
    #pragma unroll
    for (int i = 0; i < 4; ++i) {
        int lin = i * 256 + t;
        int row = lin >> 3, blk = lin & 7;
        int oct = blk ^ (row & 7);
        pa[i] = A  + (size_t)(bm * 128 + row) * Kd + oct * 8;
        pb[i] = Bt + (size_t)(bn * 128 + row) * Kd + oct * 8;
        la[i] = sA + lin * 8;
        lb[i] = sB + lin * 8;
    }

    f32x4 acc[4][4];
    #pragma unroll
    for (int i = 0; i < 4; ++i)
        #pragma unroll
        for (int j = 0; j < 4; ++j)
            #pragma unroll
            for (int r = 0; r < 4; ++r) acc[i][j][r] = 0.f;

    const char* sAc = (const char*)sA;
    const char* sBc = (const char*)sB;
    int rowA0 = wm * 64 + c, rowB0 = wn * 64 + c;
    int sw = (c & 7);

    int nkt = Kd >> 6;
    for (int kt = 0; kt < nkt; ++kt) {
        #pragma unroll
        for (int i = 0; i < 4; ++i) {
            g2l16(pa[i], la[i]);
            g2l16(pb[i], lb[i]);
            pa[i] += 64; pb[i] += 64;
        }
        __syncthreads();
        #pragma unroll
        for (int s = 0; s < 2; ++s) {
            bf16x8 af[4], bfv[4];
            int so = (s << 2) | quad;
            #pragma unroll
            for (int mt = 0; mt < 4; ++mt)
                af[mt] = *(const bf16x8*)(sAc + (rowA0 + mt * 16) * 128 + ((so ^ sw) * 16));
            #pragma unroll
            for (int nt = 0; nt < 4; ++nt)
                bfv[nt] = *(const bf16x8*)(sBc + (rowB0 + nt * 16) * 128 + ((so ^ sw) * 16));
            #pragma unroll
            for (int mt = 0; mt < 4; ++mt)
                #pragma unroll
                for (int nt = 0; nt < 4; ++nt)
                    acc[mt][nt] = __builtin_amdgcn_mfma_f32_16x16x32_bf16(af[mt], bfv[nt], acc[mt][nt], 0, 0, 0);
        }
        __syncthreads();
    }

    float bv[4];
    #pragma unroll
    for (int nt = 0; nt < 4; ++nt) bv[nt] = bias[bn * 128 + wn * 64 + nt * 16 + c];
    #pragma unroll
    for (int mt = 0; mt < 4; ++mt)
        #pragma unroll
        for (int r = 0; r < 4; ++r) {
            int row = bm * 128 + wm * 64 + mt * 16 + quad * 4 + r;
            float* cp = C + (size_t)row * N + bn * 128 + wn * 64 + c;
            #pragma unroll
            for (int nt = 0; nt < 4; ++nt) cp[nt * 16] = acc[mt][nt][r] + bv[nt];
        }
}

// ---------------- fixup: L2-normalize XQ/XK, XV <- ln(xv-xk)+xk (per (b,l,h) row of 64) ----------------
__global__ __launch_bounds__(256) void fixup_kernel(float* __restrict__ XQ, float* __restrict__ XK,
                                                    float* __restrict__ XV,
                                                    const float* __restrict__ lnw_g,
                                                    const float* __restrict__ lnb_g) {
    int g = blockIdx.x * 4 + (threadIdx.x >> 6); // (b*L+l)*H + h
    int d = threadIdx.x & 63;
    int h = g & (Hh - 1);
    size_t base = (size_t)(g >> 5) * Dd + h * 64 + d;
    float q = XQ[base], k = XK[base], v = XV[base];
    float nq = sqrtf(wsum64(q * q)); q /= fmaxf(nq, 1e-12f);
    float nk = sqrtf(wsum64(k * k)); k /= fmaxf(nk, 1e-12f);
    float diff = v - k;
    float mu = wsum64(diff) * (1.f / 64.f);
    float cc = diff - mu;
    float var = wsum64(cc * cc) * (1.f / 63.f); // ddof=1
    float vn = lnw_g[h * 64 + d] * cc / (sqrtf(var) + 1e-8f) + lnb_g[h * 64 + d] + k;
    XQ[base] = q; XK[base] = k; XV[base] = vn;
}

// ---------------- lr: s[b,h,l] = sigmoid(hs[b,l,:]·lr_w[h,:] + lr_b[h]) / (HD*K) ----------------
__global__ __launch_bounds__(256) void lr_kernel(const float* __restrict__ hs,
                                                 const float* __restrict__ lrw,
                                                 const float* __restrict__ lrb,
                                                 float* __restrict__ lr_out) {
    int tok = blockIdx.x; // b*L + l
    int t = threadIdx.x;
    int h = t >> 3, j0 = t & 7;
    const float* row = hs + (size_t)tok * Dd;
    const float* wr = lrw + (size_t)h * Dd;
    float p = 0.f;
    for (int j = j0 * 4; j < Dd; j += 32) {
        float4 a = *(const float4*)(row + j);
        float4 w = *(const float4*)(wr + j);
        p += a.x * w.x + a.y * w.y + a.z * w.z + a.w * w.w;
    }
    __shared__ float red[32][8];
    red[h][j0] = p;
    __syncthreads();
    if (t < 32) {
        float s = 0.f;
        #pragma unroll
        for (int i = 0; i < 8; ++i) s += red[t][i];
        s += lrb[t];
        s = 1.f / (1.f + expf(-s));
        s *= 1.0f / (HD * MBK);
        int b = tok >> 12, l = tok & (Ls - 1);
        lr_out[(size_t)(b * Hh + t) * Ls + l] = s;
    }
}

// ---------------- sequential TTT scan: one block per (b,h) chain ----------------
__global__ __launch_bounds__(256) void scan_kernel(const float* __restrict__ XQ,
                                                   const float* __restrict__ XK,
                                                   const float* __restrict__ XV,
                                                   const float* __restrict__ lrbuf,
                                                   const float* __restrict__ W1in,
                                                   const float* __restrict__ b1in,
                                                   const float* __restrict__ lnw_g,
                                                   const float* __restrict__ lnb_g,
                                                   float* __restrict__ Y) {
    int bh = blockIdx.x;          // b*H + h
    int b = bh >> 5, h = bh & 31;
    int t = threadIdx.x;
    int d = t & 63, w = t >> 6;

    __shared__ float W1s[64 * 64];
    __shared__ float b1s[64], lnw[64], lnb[64], sv[16];
    __shared__ float xqs[16 * 68], xks[16 * 68], xvs[16 * 68], grd[16 * 68];
    __shared__ float att[16 * 17];

    #pragma unroll
    for (int i = 0; i < 16; ++i) W1s[i * 256 + t] = W1in[(size_t)h * 4096 + i * 256 + t];
    if (t < 64) {
        b1s[t] = b1in[h * 64 + t];
        lnw[t] = lnw_g[h * 64 + t];
        lnb[t] = lnb_g[h * 64 + t];
    }
    __syncthreads();

    const float* lrp = lrbuf + (size_t)bh * Ls;

    for (int n = 0; n < NMBc; ++n) {
        int l0 = n * 16;
        // ---- stage tiles ----
        #pragma unroll
        for (int i = 0; i < 4; ++i) {
            int e = i * 256 + t; int k = e >> 6; int dd = e & 63;
            size_t ga = ((size_t)b * Ls + l0 + k) * Dd + h * 64 + dd;
            xqs[k * 68 + dd] = XQ[ga];
            xks[k * 68 + dd] = XK[ga];
            xvs[k * 68 + dd] = XV[ga];
        }
        if (t < 16) sv[t] = lrp[l0 + t];
        __syncthreads();

        // ---- Phase A: Z1 = xk@W1 + b1 ; grad = ln_fused_l2_bwd ----
        float z[4];
        #pragma unroll
        for (int i = 0; i < 4; ++i) z[i] = b1s[d];
        for (int jb = 0; jb < 16; ++jb) {
            float wv0 = W1s[(jb * 4 + 0) * 64 + d];
            float wv1 = W1s[(jb * 4 + 1) * 64 + d];
            float wv2 = W1s[(jb * 4 + 2) * 64 + d];
            float wv3 = W1s[(jb * 4 + 3) * 64 + d];
            #pragma unroll
            for (int i = 0; i < 4; ++i) {
                float4 xkv = *(const float4*)&xks[(4 * w + i) * 68 + jb * 4];
                z[i] += xkv.x * wv0 + xkv.y * wv1 + xkv.z * wv2 + xkv.w * wv3;
            }
        }
        #pragma unroll
        for (int i = 0; i < 4; ++i) {
            int k = 4 * w + i;
            float mu = wsum64(z[i]) * (1.f / 64.f);
            float cc = z[i] - mu;
            float var = wsum64(cc * cc) * (1.f / 64.f);
            float rstd = rsqrtf(var + 1e-6f);
            float xh = cc * rstd;
            float tgt = xvs[k * 68 + d] - xks[k * 68 + d];
            float gg = (lnw[d] * xh + lnb[d] - tgt) * lnw[d];
            float sg = wsum64(gg);
            float sxg = wsum64(xh * gg);
            grd[k * 68 + d] = (64.f * gg - sg - xh * sxg) * rstd * (1.f / 64.f);
        }
        // ---- Attn1 = xq @ xk^T (full 16x16; tril applied later) ----
        {
            int ii = t >> 4, jj = t & 15;
            float a = 0.f;
            #pragma unroll
            for (int db = 0; db < 16; ++db) {
                float4 qv = *(const float4*)&xqs[ii * 68 + db * 4];
                float4 kv = *(const float4*)&xks[jj * 68 + db * 4];
                a += qv.x * kv.x + qv.y * kv.y + qv.z * kv.z + qv.w * kv.w;
            }
            att[ii * 17 + jj] = a;
        }
        __syncthreads();

        // ---- Phase C: Z1_bar, output ----
        float zb[4];
        #pragma unroll
        for (int i = 0; i < 4; ++i) zb[i] = b1s[d];
        for (int jb = 0; jb < 16; ++jb) {
            float wv0 = W1s[(jb * 4 + 0) * 64 + d];
            float wv1 = W1s[(jb * 4 + 1) * 64 + d];
            float wv2 = W1s[(jb * 4 + 2) * 64 + d];
            float wv3 = W1s[(jb * 4 + 3) * 64 + d];
            #pragma unroll
            for (int i = 0; i < 4; ++i) {
                float4 qv = *(const float4*)&xqs[(4 * w + i) * 68 + jb * 4];
                zb[i] += qv.x * wv0 + qv.y * wv1 + qv.z * wv2 + qv.w * wv3;
            }
        }
        float run = 0.f; int jdone = 0;
        float b1new = 0.f;
        #pragma unroll
        for (int i = 0; i < 4; ++i) {
            int k = 4 * w + i;
            while (jdone <= k) { run += sv[jdone] * grd[jdone * 68 + d]; ++jdone; }
            float asum = 0.f;
            for (int j = 0; j <= k; ++j) asum += sv[j] * att[k * 17 + j] * grd[j * 68 + d];
            float zv = zb[i] - asum - run;   // zb already contains +b1
            float mu = wsum64(zv) * (1.f / 64.f);
            float cc = zv - mu;
            float var = wsum64(cc * cc) * (1.f / 64.f);
            float rstd = rsqrtf(var + 1e-6f);
            float o = lnw[d] * cc * rstd + lnb[d] + xqs[k * 68 + d];
            Y[((size_t)b * Ls + l0 + k) * Dd + h * 64 + d] = o;
        }
        if (w == 3) b1new = b1s[d] - run;
        __syncthreads();

        // ---- Phase D: W1 -= (s*xk)^T @ grad ; b1 update ----
        float upd[16];
        #pragma unroll
        for (int jj = 0; jj < 16; ++jj) upd[jj] = 0.f;
        for (int j = 0; j < 16; ++j) {
            float sg = sv[j] * grd[j * 68 + d];
            #pragma unroll
            for (int q4 = 0; q4 < 4; ++q4) {
                float4 xx = *(const float4*)&xks[j * 68 + w * 16 + q4 * 4];
                upd[q4 * 4 + 0] += xx.x * sg;
                upd[q4 * 4 + 1] += xx.y * sg;
                upd[q4 * 4 + 2] += xx.z * sg;
                upd[q4 * 4 + 3] += xx.w * sg;
            }
        }
        #pragma unroll
        for (int jj = 0; jj < 16; ++jj) W1s[(w * 16 + jj) * 64 + d] -= upd[jj];
        if (w == 3) b1s[d] = b1new;
        __syncthreads();
    }
}

// ---------------- post layernorm over D + cast to bf16 ----------------
__global__ __launch_bounds__(256) void postnorm_kernel(const float* __restrict__ Y,
                                                       const float* __restrict__ pw,
                                                       const float* __restrict__ pb,
                                                       unsigned short* __restrict__ Yb) {
    int tok = blockIdx.x, t = threadIdx.x;
    const float* row = Y + (size_t)tok * Dd;
    int c0 = t * 4, c1 = 1024 + t * 4;
    float4 v0 = *(const float4*)(row + c0);
    float4 v1 = *(const float4*)(row + c1);
    float s1 = v0.x + v0.y + v0.z + v0.w + v1.x + v1.y + v1.z + v1.w;
    float s2 = v0.x * v0.x + v0.y * v0.y + v0.z * v0.z + v0.w * v0.w +
               v1.x * v1.x + v1.y * v1.y + v1.z * v1.z + v1.w * v1.w;
    s1 = wsum64(s1); s2 = wsum64(s2);
    __shared__ float r1[4], r2[4];
    if ((t & 63) == 0) { r1[t >> 6] = s1; r2[t >> 6] = s2; }
    __syncthreads();
    float S1 = r1[0] + r1[1] + r1[2] + r1[3];
    float S2 = r2[0] + r2[1] + r2[2] + r2[3];
    float mu = S1 * (1.f / 2048.f);
    float var = S2 * (1.f / 2048.f) - mu * mu;
    float rstd = rsqrtf(var + 1e-6f);
    float4 w0 = *(const float4*)(pw + c0), b0 = *(const float4*)(pb + c0);
    float4 w1 = *(const float4*)(pw + c1), b1 = *(const float4*)(pb + c1);
    ushort4 o0, o1;
    o0.x = f2bf((v0.x - mu) * rstd * w0.x + b0.x);
    o0.y = f2bf((v0.y - mu) * rstd * w0.y + b0.y);
    o0.z = f2bf((v0.z - mu) * rstd * w0.z + b0.z);
    o0.w = f2bf((v0.w - mu) * rstd * w0.w + b0.w);
    o1.x = f2bf((v1.x - mu) * rstd * w1.x + b1.x);
    o1.y = f2bf((v1.y - mu) * rstd * w1.y + b1.y);
    o1.z = f2bf((v1.z - mu) * rstd * w1.z + b1.z);
    o1.w = f2bf((v1.w - mu) * rstd * w1.w + b1.w);
    *(ushort4*)(Yb + (size_t)tok * Dd + c0) = o0;
    *(ushort4*)(Yb + (size_t)tok * Dd + c1) = o1;
}

extern "C" void kernel_launch(void* const* d_in, const int* in_sizes, int n_in,
                              void* d_out, int out_size, void* d_ws, size_t ws_size,
                              hipStream_t stream) {
    const float* hs   = (const float*)d_in[0];
    const float* wq_w = (const float*)d_in[1];
    const float* wq_b = (const float*)d_in[2];
    const float* wk_w = (const float*)d_in[3];
    const float* wk_b = (const float*)d_in[4];
    const float* wv_w = (const float*)d_in[5];
    const float* wv_b = (const float*)d_in[6];
    const float* wo_w = (const float*)d_in[7];
    const float* wo_b = (const float*)d_in[8];
    const float* lnw  = (const float*)d_in[9];
    const float* lnb  = (const float*)d_in[10];
    const float* lr_w = (const float*)d_in[11];
    const float* lr_b = (const float*)d_in[12];
    const float* W1   = (const float*)d_in[13];
    const float* b1   = (const float*)d_in[14];
    const float* pnw  = (const float*)d_in[15];
    const float* pnb  = (const float*)d_in[16];
    float* out = (float*)d_out;

    char* ws = (char*)d_ws;
    size_t off = 0;
    auto alloc = [&](size_t bytes) -> void* {
        void* p = ws + off; off += (bytes + 255) & ~(size_t)255; return p;
    };
    unsigned short* hsb = (unsigned short*)alloc((size_t)MTOK * Dd * 2);
    unsigned short* wtb = (unsigned short*)alloc((size_t)Dd * Dd * 2);
    float* XQ = (float*)alloc((size_t)MTOK * Dd * 4);
    float* XK = (float*)alloc((size_t)MTOK * Dd * 4);
    float* XV = (float*)alloc((size_t)MTOK * Dd * 4);
    float* lrbuf = (float*)alloc((size_t)Bb * Hh * Ls * 4);
    float* Y = XQ;                 // safe alias: scan block (b,h) writes only its own
                                   // h-column at rows <= its current step (already staged)
    unsigned short* Yb = hsb;      // hsb dead after QKV GEMMs

    dim3 blk(256);
    cast_hs_kernel<<<dim3(MTOK * Dd / 1024), blk, 0, stream>>>(hs, hsb);

    transpose_cast_kernel<<<dim3(1024), blk, 0, stream>>>(wq_w, wtb);
    gemm_bt_kernel<<<dim3(64, 16), blk, 0, stream>>>(hsb, wtb, wq_b, XQ, MTOK, Dd, Dd);
    transpose_cast_kernel<<<dim3(1024), blk, 0, stream>>>(wk_w, wtb);
    gemm_bt_kernel<<<dim3(64, 16), blk, 0, stream>>>(hsb, wtb, wk_b, XK, MTOK, Dd, Dd);
    transpose_cast_kernel<<<dim3(1024), blk, 0, stream>>>(wv_w, wtb);
    gemm_bt_kernel<<<dim3(64, 16), blk, 0, stream>>>(hsb, wtb, wv_b, XV, MTOK, Dd, Dd);

    fixup_kernel<<<dim3(Bb * Ls * Hh / 4), blk, 0, stream>>>(XQ, XK, XV, lnw, lnb);
    lr_kernel<<<dim3(MTOK), blk, 0, stream>>>(hs, lr_w, lr_b, lrbuf);

    scan_kernel<<<dim3(Bb * Hh), blk, 0, stream>>>(XQ, XK, XV, lrbuf, W1, b1, lnw, lnb, Y);

    postnorm_kernel<<<dim3(MTOK), blk, 0, stream>>>(Y, pnw, pnb, Yb);

    transpose_cast_kernel<<<dim3(1024), blk, 0, stream>>>(wo_w, wtb);
    gemm_bt_kernel<<<dim3(64, 16), blk, 0, stream>>>(Yb, wtb, wo_b, out, MTOK, Dd, Dd);
}

// Round 2
// 3026.008 us; speedup vs baseline: 1.3525x; 1.3525x over previous
//
#include <hip/hip_runtime.h>
#include <hip/hip_bf16.h>
#include <cstdint>
#include <cstddef>

#define DEV __device__ __forceinline__

constexpr int Bb = 2, Ls = 4096, Dd = 2048, Hh = 32, HD = 64, MBK = 16, NMBc = 256;
constexpr int MTOK = Bb * Ls; // 8192 tokens

typedef __bf16 bf16x8 __attribute__((ext_vector_type(8)));
typedef float  f32x4  __attribute__((ext_vector_type(4)));

DEV unsigned short f2bf(float f) {
    union { float f; unsigned int u; } x; x.f = f;
    unsigned int u = x.u;
    return (unsigned short)((u + 0x7fffu + ((u >> 16) & 1u)) >> 16);
}

DEV float wsum64(float v) {
    #pragma unroll
    for (int m = 32; m >= 1; m >>= 1) v += __shfl_xor(v, m, 64);
    return v;
}

DEV float qsum16(float v) {
    v += __shfl_xor(v, 1, 64);
    v += __shfl_xor(v, 2, 64);
    v += __shfl_xor(v, 4, 64);
    v += __shfl_xor(v, 8, 64);
    return v;
}

DEV void g2l16(const void* g, void* l) {
    __builtin_amdgcn_global_load_lds(
        (__attribute__((address_space(1))) void*)(g),
        (__attribute__((address_space(3))) void*)(l), 16, 0, 0);
}

// ---------------- cast hidden_states fp32 -> bf16 ----------------
__global__ __launch_bounds__(256) void cast_hs_kernel(const float* __restrict__ src,
                                                      unsigned short* __restrict__ dst) {
    int i = (blockIdx.x * 256 + threadIdx.x) * 4;
    float4 v = *(const float4*)(src + i);
    ushort4 o; o.x = f2bf(v.x); o.y = f2bf(v.y); o.z = f2bf(v.z); o.w = f2bf(v.w);
    *(ushort4*)(dst + i) = o;
}

// ---------------- transpose + cast weight: W[k][n] fp32 -> Wt[n][k] bf16 ----------------
__global__ __launch_bounds__(256) void transpose_cast_kernel(const float* __restrict__ W,
                                                             unsigned short* __restrict__ Wt) {
    __shared__ float tile[64][65];
    int bx = blockIdx.x & 31;   // k-tile
    int by = blockIdx.x >> 5;   // n-tile
    int t = threadIdx.x;
    int r = t >> 4, c4 = (t & 15) * 4;
    #pragma unroll
    for (int i = 0; i < 4; ++i) {
        int row = r + i * 16;
        float4 v = *(const float4*)(W + (size_t)(bx * 64 + row) * Dd + by * 64 + c4);
        tile[row][c4 + 0] = v.x; tile[row][c4 + 1] = v.y;
        tile[row][c4 + 2] = v.z; tile[row][c4 + 3] = v.w;
    }
    __syncthreads();
    #pragma unroll
    for (int i = 0; i < 4; ++i) {
        int row = r + i * 16; // n index
        ushort4 o;
        o.x = f2bf(tile[c4 + 0][row]); o.y = f2bf(tile[c4 + 1][row]);
        o.z = f2bf(tile[c4 + 2][row]); o.w = f2bf(tile[c4 + 3][row]);
        *(ushort4*)(Wt + (size_t)(by * 64 + row) * Dd + bx * 64 + c4) = o;
    }
}

// ---------------- bf16 MFMA GEMM:  C[M,N] = A[M,K] @ Bt[N,K]^T + bias ----------------
__global__ __launch_bounds__(256) void gemm_bt_kernel(const unsigned short* __restrict__ A,
                                                      const unsigned short* __restrict__ Bt,
                                                      const float* __restrict__ bias,
                                                      float* __restrict__ C,
                                                      int M, int N, int Kd) {
    __shared__ unsigned short sA[128 * 64];
    __shared__ unsigned short sB[128 * 64];
    int t = threadIdx.x;
    int lane = t & 63;
    int wid = t >> 6, wm = wid >> 1, wn = wid & 1;
    int quad = lane >> 4, c = lane & 15;
    int bm = blockIdx.x, bn = blockIdx.y;

    const unsigned short* pa[4]; const unsigned short* pb[4];
    unsigned short* la[4]; unsigned short* lb[4];
    #pragma unroll
    for (int i = 0; i < 4; ++i) {
        int lin = i * 256 + t;
        int row = lin >> 3, blk = lin & 7;
        int oct = blk ^ (row & 7);
        pa[i] = A  + (size_t)(bm * 128 + row) * Kd + oct * 8;
        pb[i] = Bt + (size_t)(bn * 128 + row) * Kd + oct * 8;
        la[i] = sA + lin * 8;
        lb[i] = sB + lin * 8;
    }

    f32x4 acc[4][4];
    #pragma unroll
    for (int i = 0; i < 4; ++i)
        #pragma unroll
        for (int j = 0; j < 4; ++j)
            #pragma unroll
            for (int r = 0; r < 4; ++r) acc[i][j][r] = 0.f;

    const char* sAc = (const char*)sA;
    const char* sBc = (const char*)sB;
    int rowA0 = wm * 64 + c, rowB0 = wn * 64 + c;
    int sw = (c & 7);

    int nkt = Kd >> 6;
    for (int kt = 0; kt < nkt; ++kt) {
        #pragma unroll
        for (int i = 0; i < 4; ++i) {
            g2l16(pa[i], la[i]);
            g2l16(pb[i], lb[i]);
            pa[i] += 64; pb[i] += 64;
        }
        __syncthreads();
        #pragma unroll
        for (int s = 0; s < 2; ++s) {
            bf16x8 af[4], bfv[4];
            int so = (s << 2) | quad;
            #pragma unroll
            for (int mt = 0; mt < 4; ++mt)
                af[mt] = *(const bf16x8*)(sAc + (rowA0 + mt * 16) * 128 + ((so ^ sw) * 16));
            #pragma unroll
            for (int nt = 0; nt < 4; ++nt)
                bfv[nt] = *(const bf16x8*)(sBc + (rowB0 + nt * 16) * 128 + ((so ^ sw) * 16));
            #pragma unroll
            for (int mt = 0; mt < 4; ++mt)
                #pragma unroll
                for (int nt = 0; nt < 4; ++nt)
                    acc[mt][nt] = __builtin_amdgcn_mfma_f32_16x16x32_bf16(af[mt], bfv[nt], acc[mt][nt], 0, 0, 0);
        }
        __syncthreads();
    }

    float bv[4];
    #pragma unroll
    for (int nt = 0; nt < 4; ++nt) bv[nt] = bias[bn * 128 + wn * 64 + nt * 16 + c];
    #pragma unroll
    for (int mt = 0; mt < 4; ++mt)
        #pragma unroll
        for (int r = 0; r < 4; ++r) {
            int row = bm * 128 + wm * 64 + mt * 16 + quad * 4 + r;
            float* cp = C + (size_t)row * N + bn * 128 + wn * 64 + c;
            #pragma unroll
            for (int nt = 0; nt < 4; ++nt) cp[nt * 16] = acc[mt][nt][r] + bv[nt];
        }
}

// ---------------- fixup: L2-normalize XQ/XK, XV <- ln(xv-xk)+xk ----------------
__global__ __launch_bounds__(256) void fixup_kernel(float* __restrict__ XQ, float* __restrict__ XK,
                                                    float* __restrict__ XV,
                                                    const float* __restrict__ lnw_g,
                                                    const float* __restrict__ lnb_g) {
    int g = blockIdx.x * 4 + (threadIdx.x >> 6); // (b*L+l)*H + h
    int d = threadIdx.x & 63;
    int h = g & (Hh - 1);
    size_t base = (size_t)(g >> 5) * Dd + h * 64 + d;
    float q = XQ[base], k = XK[base], v = XV[base];
    float nq = sqrtf(wsum64(q * q)); q /= fmaxf(nq, 1e-12f);
    float nk = sqrtf(wsum64(k * k)); k /= fmaxf(nk, 1e-12f);
    float diff = v - k;
    float mu = wsum64(diff) * (1.f / 64.f);
    float cc = diff - mu;
    float var = wsum64(cc * cc) * (1.f / 63.f); // ddof=1
    float vn = lnw_g[h * 64 + d] * cc / (sqrtf(var) + 1e-8f) + lnb_g[h * 64 + d] + k;
    XQ[base] = q; XK[base] = k; XV[base] = vn;
}

// ---------------- lr: s[b,h,l] = sigmoid(hs[b,l,:]·lr_w[h,:] + lr_b[h]) / (HD*K) ----------------
__global__ __launch_bounds__(256) void lr_kernel(const float* __restrict__ hs,
                                                 const float* __restrict__ lrw,
                                                 const float* __restrict__ lrb,
                                                 float* __restrict__ lr_out) {
    int tok = blockIdx.x; // b*L + l
    int t = threadIdx.x;
    int h = t >> 3, j0 = t & 7;
    const float* row = hs + (size_t)tok * Dd;
    const float* wr = lrw + (size_t)h * Dd;
    float p = 0.f;
    for (int j = j0 * 4; j < Dd; j += 32) {
        float4 a = *(const float4*)(row + j);
        float4 w = *(const float4*)(wr + j);
        p += a.x * w.x + a.y * w.y + a.z * w.z + a.w * w.w;
    }
    __shared__ float red[32][8];
    red[h][j0] = p;
    __syncthreads();
    if (t < 32) {
        float s = 0.f;
        #pragma unroll
        for (int i = 0; i < 8; ++i) s += red[t][i];
        s += lrb[t];
        s = 1.f / (1.f + expf(-s));
        s *= 1.0f / (HD * MBK);
        int b = tok >> 12, l = tok & (Ls - 1);
        lr_out[(size_t)(b * Hh + t) * Ls + l] = s;
    }
}

// ---------------- MFMA TTT scan: ONE WAVE per (b,h) chain ----------------
// Layout identities used (mfma_f32_16x16x32_bf16):
//   A-frag: A[m=lane&15][k=(lane>>4)*8+j]   B-frag: B[k=(lane>>4)*8+j][n=lane&15]
//   C:      C[row=(lane>>4)*4+r][col=lane&15]
// W1 master: fp32 in LDS, TRANSPOSED Wb[col][row], stride 68 (b128-friendly, ~conflict-free).
// X@W1 matmuls use hi/lo bf16 split of W1 (fp32-equivalent W1 precision).
__global__ __launch_bounds__(64, 1) void scan_kernel(const float* __restrict__ XQ,
                                                     const float* __restrict__ XK,
                                                     const float* __restrict__ XV,
                                                     const float* __restrict__ lrbuf,
                                                     const float* __restrict__ W1in,
                                                     const float* __restrict__ b1in,
                                                     const float* __restrict__ lnw_g,
                                                     const float* __restrict__ lnb_g,
                                                     float* __restrict__ Y) {
    int bh = blockIdx.x;          // b*H + h
    int b = bh >> 5, h = bh & 31;
    int lane = threadIdx.x;       // 64 threads = 1 wave
    int q = lane >> 4, n = lane & 15;
    float m01 = (q < 2) ? 1.f : 0.f;   // mask: quads 0,1 hold real K=16 data in padded frags

    __shared__ float xqs[16 * 68];
    __shared__ float xks[16 * 68];
    __shared__ float Wb[64 * 68];      // Wb[col*68 + row] = W1[row][col]
    __shared__ float gbuf[16 * 68];    // grad bounce [k][col]
    __shared__ float att[16 * 17];     // -masked eta*(Attn+1) bounce

    // ---- init W1 (transposed into LDS) ----
    #pragma unroll 4
    for (int j = 0; j < 64; ++j)
        Wb[lane * 68 + j] = W1in[(size_t)h * 4096 + j * 64 + lane];

    float b1v[4], lnwv[4], lnbv[4];
    #pragma unroll
    for (int t = 0; t < 4; ++t) {
        b1v[t] = b1in[h * 64 + 16 * t + n];
        lnwv[t] = lnw_g[h * 64 + 16 * t + n];
        lnbv[t] = lnb_g[h * 64 + 16 * t + n];
    }

    const size_t gbase = ((size_t)b * Ls) * Dd + h * 64;
    const float* lrp = lrbuf + (size_t)bh * Ls;

    // ---- prefetch step-0 tiles into registers ----
    float4 pre[8];
    #pragma unroll
    for (int i = 0; i < 4; ++i) {
        pre[i]     = *(const float4*)(XQ + gbase + (size_t)(4 * i + q) * Dd + 4 * n);
        pre[4 + i] = *(const float4*)(XK + gbase + (size_t)(4 * i + q) * Dd + 4 * n);
    }

    const f32x4 zero4 = {0.f, 0.f, 0.f, 0.f};

    for (int nmb = 0; nmb < NMBc; ++nmb) {
        int l0 = nmb * 16;
        // ---- stage current tiles to LDS ----
        #pragma unroll
        for (int i = 0; i < 4; ++i) {
            *(float4*)&xqs[(4 * i + q) * 68 + 4 * n] = pre[i];
            *(float4*)&xks[(4 * i + q) * 68 + 4 * n] = pre[4 + i];
        }
        // ---- prefetch next step ----
        int l0n = (nmb < NMBc - 1) ? l0 + 16 : l0;
        #pragma unroll
        for (int i = 0; i < 4; ++i) {
            pre[i]     = *(const float4*)(XQ + gbase + (size_t)(l0n + 4 * i + q) * Dd + 4 * n);
            pre[4 + i] = *(const float4*)(XK + gbase + (size_t)(l0n + 4 * i + q) * Dd + 4 * n);
        }
        // ---- eta scalars ----
        float svn = lrp[l0 + n];                                   // sv[n]  (attn col)
        float4 svq = *(const float4*)(lrp + l0 + 4 * q);           // sv[4q+r]
        float4 sv8a = *(const float4*)(lrp + l0 + ((8 * q) & 15));     // sv[8q..8q+3]
        float4 sv8b = *(const float4*)(lrp + l0 + ((8 * q) & 15) + 4); // sv[8q+4..8q+7]
        // ---- C-layout elementwise operands straight from global ----
        float xqC[4][4], xkC[4][4], xvC[4][4];
        #pragma unroll
        for (int t = 0; t < 4; ++t)
            #pragma unroll
            for (int r = 0; r < 4; ++r) {
                size_t idx = gbase + (size_t)(l0 + 4 * q + r) * Dd + 16 * t + n;
                xqC[t][r] = XQ[idx]; xkC[t][r] = XK[idx]; xvC[t][r] = XV[idx];
            }
        // ---- raw xk for the (sv*xk)^T update operand (A-frag positions) ----
        float axr[4][8];
        #pragma unroll
        for (int tm = 0; tm < 4; ++tm)
            #pragma unroll
            for (int jj = 0; jj < 8; ++jj)
                axr[tm][jj] = XK[gbase + (size_t)(l0 + ((8 * q + jj) & 15)) * Dd + 16 * tm + n];

        // ---- A-frags of xq, xk (bf16) ----
        bf16x8 qf0, qf1, kf0, kf1;
        {
            const float* pq0 = &xqs[n * 68 + 8 * q];
            const float* pq1 = &xqs[n * 68 + 32 + 8 * q];
            const float* pk0 = &xks[n * 68 + 8 * q];
            const float* pk1 = &xks[n * 68 + 32 + 8 * q];
            #pragma unroll
            for (int j = 0; j < 8; ++j) {
                qf0[j] = (__bf16)pq0[j]; qf1[j] = (__bf16)pq1[j];
                kf0[j] = (__bf16)pk0[j]; kf1[j] = (__bf16)pk1[j];
            }
        }
        // ---- Attn = xq @ xk^T  (B-frag of xk^T == A-frag of xk) ----
        f32x4 aacc = __builtin_amdgcn_mfma_f32_16x16x32_bf16(qf1, kf1, zero4, 0, 0, 0);
        aacc = __builtin_amdgcn_mfma_f32_16x16x32_bf16(qf0, kf0, aacc, 0, 0, 0);

        // ---- per-slab W1 pass: Z1 += xk@W1, Zbar += xq@W1 (hi/lo split) ----
        f32x4 z1a[4], zba[4];
        #pragma unroll
        for (int ts = 0; ts < 4; ++ts) {
            const float* w0 = &Wb[(16 * ts + n) * 68 + 8 * q];
            const float* w1p = &Wb[(16 * ts + n) * 68 + 32 + 8 * q];
            bf16x8 h0, l0f, h1, l1f;
            #pragma unroll
            for (int j = 0; j < 8; ++j) {
                float wa = w0[j];  __bf16 ha = (__bf16)wa; h0[j] = ha; l0f[j] = (__bf16)(wa - (float)ha);
                float wb2 = w1p[j]; __bf16 hb = (__bf16)wb2; h1[j] = hb; l1f[j] = (__bf16)(wb2 - (float)hb);
            }
            f32x4 za = __builtin_amdgcn_mfma_f32_16x16x32_bf16(kf0, h0, zero4, 0, 0, 0);
            za = __builtin_amdgcn_mfma_f32_16x16x32_bf16(kf1, h1, za, 0, 0, 0);
            za = __builtin_amdgcn_mfma_f32_16x16x32_bf16(kf0, l0f, za, 0, 0, 0);
            za = __builtin_amdgcn_mfma_f32_16x16x32_bf16(kf1, l1f, za, 0, 0, 0);
            z1a[ts] = za;
            f32x4 zb = __builtin_amdgcn_mfma_f32_16x16x32_bf16(qf0, h0, zero4, 0, 0, 0);
            zb = __builtin_amdgcn_mfma_f32_16x16x32_bf16(qf1, h1, zb, 0, 0, 0);
            zb = __builtin_amdgcn_mfma_f32_16x16x32_bf16(qf0, l0f, zb, 0, 0, 0);
            zb = __builtin_amdgcn_mfma_f32_16x16x32_bf16(qf1, l1f, zb, 0, 0, 0);
            zba[ts] = zb;
        }

        // ---- phase A: grad = ln_fused_l2_bwd(Z1, xv-xk) ----
        float gC[4][4];
        #pragma unroll
        for (int r = 0; r < 4; ++r) {
            float zr[4];
            #pragma unroll
            for (int ts = 0; ts < 4; ++ts) zr[ts] = z1a[ts][r] + b1v[ts];
            float s1 = zr[0] + zr[1] + zr[2] + zr[3];
            float s2 = zr[0] * zr[0] + zr[1] * zr[1] + zr[2] * zr[2] + zr[3] * zr[3];
            s1 = qsum16(s1); s2 = qsum16(s2);
            float mu = s1 * (1.f / 64.f);
            float var = s2 * (1.f / 64.f) - mu * mu;
            float rstd = rsqrtf(var + 1e-6f);
            float xh[4], g[4];
            float sg = 0.f, sxg = 0.f;
            #pragma unroll
            for (int ts = 0; ts < 4; ++ts) {
                xh[ts] = (zr[ts] - mu) * rstd;
                float tgt = xvC[ts][r] - xkC[ts][r];
                g[ts] = (lnwv[ts] * xh[ts] + lnbv[ts] - tgt) * lnwv[ts];
                sg += g[ts]; sxg += xh[ts] * g[ts];
            }
            sg = qsum16(sg); sxg = qsum16(sxg);
            #pragma unroll
            for (int ts = 0; ts < 4; ++ts)
                gC[ts][r] = (64.f * g[ts] - sg - xh[ts] * sxg) * rstd * (1.f / 64.f);
        }

        // ---- bounce grad and masked attn to LDS ----
        #pragma unroll
        for (int t = 0; t < 4; ++t)
            #pragma unroll
            for (int r = 0; r < 4; ++r)
                gbuf[(4 * q + r) * 68 + 16 * t + n] = gC[t][r];
        #pragma unroll
        for (int r = 0; r < 4; ++r) {
            int i = 4 * q + r;
            att[i * 17 + n] = (i >= n) ? (-svn * (aacc[r] + 1.f)) : 0.f; // NEGATED
        }

        // ---- read back: amFrag (A-frag, K=16 padded), grad B-frags ----
        bf16x8 amF, gF[4];
        #pragma unroll
        for (int jj = 0; jj < 8; ++jj)
            amF[jj] = (__bf16)(att[n * 17 + ((8 * q + jj) & 15)] * m01);
        #pragma unroll
        for (int ts = 0; ts < 4; ++ts)
            #pragma unroll
            for (int jj = 0; jj < 8; ++jj)
                gF[ts][jj] = (__bf16)(gbuf[((8 * q + jj) & 15) * 68 + 16 * ts + n] * m01);

        // ---- finish Zbar: -= maskedEta(Attn+1) @ grad (amF pre-negated) ----
        #pragma unroll
        for (int ts = 0; ts < 4; ++ts)
            zba[ts] = __builtin_amdgcn_mfma_f32_16x16x32_bf16(amF, gF[ts], zba[ts], 0, 0, 0);

        // ---- phase C: out = xq + ln_fwd(Zbar) ----
        #pragma unroll
        for (int r = 0; r < 4; ++r) {
            float zr[4];
            #pragma unroll
            for (int ts = 0; ts < 4; ++ts) zr[ts] = zba[ts][r] + b1v[ts];
            float s1 = zr[0] + zr[1] + zr[2] + zr[3];
            float s2 = zr[0] * zr[0] + zr[1] * zr[1] + zr[2] * zr[2] + zr[3] * zr[3];
            s1 = qsum16(s1); s2 = qsum16(s2);
            float mu = s1 * (1.f / 64.f);
            float var = s2 * (1.f / 64.f) - mu * mu;
            float rstd = rsqrtf(var + 1e-6f);
            #pragma unroll
            for (int ts = 0; ts < 4; ++ts) {
                float o = lnwv[ts] * ((zr[ts] - mu) * rstd) + lnbv[ts] + xqC[ts][r];
                Y[gbase + (size_t)(l0 + 4 * q + r) * Dd + 16 * ts + n] = o;
            }
        }

        // ---- b1 update: b1 -= sum_k sv[k]*grad[k][col] ----
        float svqr[4] = {svq.x, svq.y, svq.z, svq.w};
        #pragma unroll
        for (int ts = 0; ts < 4; ++ts) {
            float p = svqr[0] * gC[ts][0] + svqr[1] * gC[ts][1] +
                      svqr[2] * gC[ts][2] + svqr[3] * gC[ts][3];
            p += __shfl_xor(p, 16, 64);
            p += __shfl_xor(p, 32, 64);
            b1v[ts] -= p;
        }

        // ---- W1 update: W1 -= (sv∘xk)^T @ grad ----
        float sv8[8] = {sv8a.x, sv8a.y, sv8a.z, sv8a.w, sv8b.x, sv8b.y, sv8b.z, sv8b.w};
        bf16x8 axF[4];
        #pragma unroll
        for (int tm = 0; tm < 4; ++tm)
            #pragma unroll
            for (int jj = 0; jj < 8; ++jj)
                axF[tm][jj] = (__bf16)(sv8[jj] * axr[tm][jj] * m01);
        #pragma unroll
        for (int tm = 0; tm < 4; ++tm)
            #pragma unroll
            for (int tn = 0; tn < 4; ++tn) {
                f32x4 dlt = __builtin_amdgcn_mfma_f32_16x16x32_bf16(axF[tm], gF[tn], zero4, 0, 0, 0);
                float* wp = &Wb[(16 * tn + n) * 68 + 16 * tm + 4 * q];
                float4 wv = *(float4*)wp;
                wv.x -= dlt[0]; wv.y -= dlt[1]; wv.z -= dlt[2]; wv.w -= dlt[3];
                *(float4*)wp = wv;
            }
    }
}

// ---------------- post layernorm over D + cast to bf16 ----------------
__global__ __launch_bounds__(256) void postnorm_kernel(const float* __restrict__ Y,
                                                       const float* __restrict__ pw,
                                                       const float* __restrict__ pb,
                                                       unsigned short* __restrict__ Yb) {
    int tok = blockIdx.x, t = threadIdx.x;
    const float* row = Y + (size_t)tok * Dd;
    int c0 = t * 4, c1 = 1024 + t * 4;
    float4 v0 = *(const float4*)(row + c0);
    float4 v1 = *(const float4*)(row + c1);
    float s1 = v0.x + v0.y + v0.z + v0.w + v1.x + v1.y + v1.z + v1.w;
    float s2 = v0.x * v0.x + v0.y * v0.y + v0.z * v0.z + v0.w * v0.w +
               v1.x * v1.x + v1.y * v1.y + v1.z * v1.z + v1.w * v1.w;
    s1 = wsum64(s1); s2 = wsum64(s2);
    __shared__ float r1[4], r2[4];
    if ((t & 63) == 0) { r1[t >> 6] = s1; r2[t >> 6] = s2; }
    __syncthreads();
    float S1 = r1[0] + r1[1] + r1[2] + r1[3];
    float S2 = r2[0] + r2[1] + r2[2] + r2[3];
    float mu = S1 * (1.f / 2048.f);
    float var = S2 * (1.f / 2048.f) - mu * mu;
    float rstd = rsqrtf(var + 1e-6f);
    float4 w0 = *(const float4*)(pw + c0), b0 = *(const float4*)(pb + c0);
    float4 w1 = *(const float4*)(pw + c1), b1 = *(const float4*)(pb + c1);
    ushort4 o0, o1;
    o0.x = f2bf((v0.x - mu) * rstd * w0.x + b0.x);
    o0.y = f2bf((v0.y - mu) * rstd * w0.y + b0.y);
    o0.z = f2bf((v0.z - mu) * rstd * w0.z + b0.z);
    o0.w = f2bf((v0.w - mu) * rstd * w0.w + b0.w);
    o1.x = f2bf((v1.x - mu) * rstd * w1.x + b1.x);
    o1.y = f2bf((v1.y - mu) * rstd * w1.y + b1.y);
    o1.z = f2bf((v1.z - mu) * rstd * w1.z + b1.z);
    o1.w = f2bf((v1.w - mu) * rstd * w1.w + b1.w);
    *(ushort4*)(Yb + (size_t)tok * Dd + c0) = o0;
    *(ushort4*)(Yb + (size_t)tok * Dd + c1) = o1;
}

extern "C" void kernel_launch(void* const* d_in, const int* in_sizes, int n_in,
                              void* d_out, int out_size, void* d_ws, size_t ws_size,
                              hipStream_t stream) {
    const float* hs   = (const float*)d_in[0];
    const float* wq_w = (const float*)d_in[1];
    const float* wq_b = (const float*)d_in[2];
    const float* wk_w = (const float*)d_in[3];
    const float* wk_b = (const float*)d_in[4];
    const float* wv_w = (const float*)d_in[5];
    const float* wv_b = (const float*)d_in[6];
    const float* wo_w = (const float*)d_in[7];
    const float* wo_b = (const float*)d_in[8];
    const float* lnw  = (const float*)d_in[9];
    const float* lnb  = (const float*)d_in[10];
    const float* lr_w = (const float*)d_in[11];
    const float* lr_b = (const float*)d_in[12];
    const float* W1   = (const float*)d_in[13];
    const float* b1   = (const float*)d_in[14];
    const float* pnw  = (const float*)d_in[15];
    const float* pnb  = (const float*)d_in[16];
    float* out = (float*)d_out;

    char* ws = (char*)d_ws;
    size_t off = 0;
    auto alloc = [&](size_t bytes) -> void* {
        void* p = ws + off; off += (bytes + 255) & ~(size_t)255; return p;
    };
    unsigned short* hsb = (unsigned short*)alloc((size_t)MTOK * Dd * 2);
    unsigned short* wtb = (unsigned short*)alloc((size_t)Dd * Dd * 2);
    float* XQ = (float*)alloc((size_t)MTOK * Dd * 4);
    float* XK = (float*)alloc((size_t)MTOK * Dd * 4);
    float* XV = (float*)alloc((size_t)MTOK * Dd * 4);
    float* lrbuf = (float*)alloc((size_t)Bb * Hh * Ls * 4);
    float* Y = XQ;                 // safe alias (per-chain row/col ownership)
    unsigned short* Yb = hsb;      // hsb dead after QKV GEMMs

    dim3 blk(256);
    cast_hs_kernel<<<dim3(MTOK * Dd / 1024), blk, 0, stream>>>(hs, hsb);

    transpose_cast_kernel<<<dim3(1024), blk, 0, stream>>>(wq_w, wtb);
    gemm_bt_kernel<<<dim3(64, 16), blk, 0, stream>>>(hsb, wtb, wq_b, XQ, MTOK, Dd, Dd);
    transpose_cast_kernel<<<dim3(1024), blk, 0, stream>>>(wk_w, wtb);
    gemm_bt_kernel<<<dim3(64, 16), blk, 0, stream>>>(hsb, wtb, wk_b, XK, MTOK, Dd, Dd);
    transpose_cast_kernel<<<dim3(1024), blk, 0, stream>>>(wv_w, wtb);
    gemm_bt_kernel<<<dim3(64, 16), blk, 0, stream>>>(hsb, wtb, wv_b, XV, MTOK, Dd, Dd);

    fixup_kernel<<<dim3(Bb * Ls * Hh / 4), blk, 0, stream>>>(XQ, XK, XV, lnw, lnb);
    lr_kernel<<<dim3(MTOK), blk, 0, stream>>>(hs, lr_w, lr_b, lrbuf);

    scan_kernel<<<dim3(Bb * Hh), dim3(64), 0, stream>>>(XQ, XK, XV, lrbuf, W1, b1, lnw, lnb, Y);

    postnorm_kernel<<<dim3(MTOK), blk, 0, stream>>>(Y, pnw, pnb, Yb);

    transpose_cast_kernel<<<dim3(1024), blk, 0, stream>>>(wo_w, wtb);
    gemm_bt_kernel<<<dim3(64, 16), blk, 0, stream>>>(Yb, wtb, wo_b, out, MTOK, Dd, Dd);
}

// Round 3
// 1761.430 us; speedup vs baseline: 2.3235x; 1.7179x over previous
//
#include <hip/hip_runtime.h>
#include <hip/hip_bf16.h>
#include <cstdint>
#include <cstddef>

#define DEV __device__ __forceinline__

constexpr int Bb = 2, Ls = 4096, Dd = 2048, Hh = 32, HD = 64, MBK = 16, NMBc = 256;
constexpr int MTOK = Bb * Ls; // 8192 tokens

typedef __bf16 bf16x8 __attribute__((ext_vector_type(8)));
typedef float  f32x4  __attribute__((ext_vector_type(4)));

DEV unsigned short f2bf(float f) {
    union { float f; unsigned int u; } x; x.f = f;
    unsigned int u = x.u;
    return (unsigned short)((u + 0x7fffu + ((u >> 16) & 1u)) >> 16);
}
DEV float b2f(unsigned short u) {
    union { unsigned int i; float f; } x; x.i = ((unsigned int)u) << 16;
    return x.f;
}

DEV float wsum64(float v) {
    #pragma unroll
    for (int m = 32; m >= 1; m >>= 1) v += __shfl_xor(v, m, 64);
    return v;
}

DEV void g2l16(const void* g, void* l) {
    __builtin_amdgcn_global_load_lds(
        (__attribute__((address_space(1))) void*)(g),
        (__attribute__((address_space(3))) void*)(l), 16, 0, 0);
}

// ---------------- cast hidden_states fp32 -> bf16 ----------------
__global__ __launch_bounds__(256) void cast_hs_kernel(const float* __restrict__ src,
                                                      unsigned short* __restrict__ dst) {
    int i = (blockIdx.x * 256 + threadIdx.x) * 4;
    float4 v = *(const float4*)(src + i);
    ushort4 o; o.x = f2bf(v.x); o.y = f2bf(v.y); o.z = f2bf(v.z); o.w = f2bf(v.w);
    *(ushort4*)(dst + i) = o;
}

// ---------------- transpose + cast weight: W[k][n] fp32 -> Wt[n][k] bf16 ----------------
__global__ __launch_bounds__(256) void transpose_cast_kernel(const float* __restrict__ W,
                                                             unsigned short* __restrict__ Wt) {
    __shared__ float tile[64][65];
    int bx = blockIdx.x & 31;   // k-tile
    int by = blockIdx.x >> 5;   // n-tile
    int t = threadIdx.x;
    int r = t >> 4, c4 = (t & 15) * 4;
    #pragma unroll
    for (int i = 0; i < 4; ++i) {
        int row = r + i * 16;
        float4 v = *(const float4*)(W + (size_t)(bx * 64 + row) * Dd + by * 64 + c4);
        tile[row][c4 + 0] = v.x; tile[row][c4 + 1] = v.y;
        tile[row][c4 + 2] = v.z; tile[row][c4 + 3] = v.w;
    }
    __syncthreads();
    #pragma unroll
    for (int i = 0; i < 4; ++i) {
        int row = r + i * 16; // n index
        ushort4 o;
        o.x = f2bf(tile[c4 + 0][row]); o.y = f2bf(tile[c4 + 1][row]);
        o.z = f2bf(tile[c4 + 2][row]); o.w = f2bf(tile[c4 + 3][row]);
        *(ushort4*)(Wt + (size_t)(by * 64 + row) * Dd + bx * 64 + c4) = o;
    }
}

// ---------------- bf16 MFMA GEMM:  C[M,N] = A[M,K] @ Bt[N,K]^T + bias ----------------
__global__ __launch_bounds__(256) void gemm_bt_kernel(const unsigned short* __restrict__ A,
                                                      const unsigned short* __restrict__ Bt,
                                                      const float* __restrict__ bias,
                                                      float* __restrict__ C,
                                                      int M, int N, int Kd) {
    __shared__ unsigned short sA[128 * 64];
    __shared__ unsigned short sB[128 * 64];
    int t = threadIdx.x;
    int lane = t & 63;
    int wid = t >> 6, wm = wid >> 1, wn = wid & 1;
    int quad = lane >> 4, c = lane & 15;
    int bm = blockIdx.x, bn = blockIdx.y;

    const unsigned short* pa[4]; const unsigned short* pb[4];
    unsigned short* la[4]; unsigned short* lb[4];
    #pragma unroll
    for (int i = 0; i < 4; ++i) {
        int lin = i * 256 + t;
        int row = lin >> 3, blk = lin & 7;
        int oct = blk ^ (row & 7);
        pa[i] = A  + (size_t)(bm * 128 + row) * Kd + oct * 8;
        pb[i] = Bt + (size_t)(bn * 128 + row) * Kd + oct * 8;
        la[i] = sA + lin * 8;
        lb[i] = sB + lin * 8;
    }

    f32x4 acc[4][4];
    #pragma unroll
    for (int i = 0; i < 4; ++i)
        #pragma unroll
        for (int j = 0; j < 4; ++j)
            #pragma unroll
            for (int r = 0; r < 4; ++r) acc[i][j][r] = 0.f;

    const char* sAc = (const char*)sA;
    const char* sBc = (const char*)sB;
    int rowA0 = wm * 64 + c, rowB0 = wn * 64 + c;
    int sw = (c & 7);

    int nkt = Kd >> 6;
    for (int kt = 0; kt < nkt; ++kt) {
        #pragma unroll
        for (int i = 0; i < 4; ++i) {
            g2l16(pa[i], la[i]);
            g2l16(pb[i], lb[i]);
            pa[i] += 64; pb[i] += 64;
        }
        __syncthreads();
        #pragma unroll
        for (int s = 0; s < 2; ++s) {
            bf16x8 af[4], bfv[4];
            int so = (s << 2) | quad;
            #pragma unroll
            for (int mt = 0; mt < 4; ++mt)
                af[mt] = *(const bf16x8*)(sAc + (rowA0 + mt * 16) * 128 + ((so ^ sw) * 16));
            #pragma unroll
            for (int nt = 0; nt < 4; ++nt)
                bfv[nt] = *(const bf16x8*)(sBc + (rowB0 + nt * 16) * 128 + ((so ^ sw) * 16));
            #pragma unroll
            for (int mt = 0; mt < 4; ++mt)
                #pragma unroll
                for (int nt = 0; nt < 4; ++nt)
                    acc[mt][nt] = __builtin_amdgcn_mfma_f32_16x16x32_bf16(af[mt], bfv[nt], acc[mt][nt], 0, 0, 0);
        }
        __syncthreads();
    }

    float bv[4];
    #pragma unroll
    for (int nt = 0; nt < 4; ++nt) bv[nt] = bias[bn * 128 + wn * 64 + nt * 16 + c];
    #pragma unroll
    for (int mt = 0; mt < 4; ++mt)
        #pragma unroll
        for (int r = 0; r < 4; ++r) {
            int row = bm * 128 + wm * 64 + mt * 16 + quad * 4 + r;
            float* cp = C + (size_t)row * N + bn * 128 + wn * 64 + c;
            #pragma unroll
            for (int nt = 0; nt < 4; ++nt) cp[nt * 16] = acc[mt][nt][r] + bv[nt];
        }
}

// ---------------- fixup: L2-normalize XQ/XK, XV <- ln(xv-xk)+xk ----------------
__global__ __launch_bounds__(256) void fixup_kernel(float* __restrict__ XQ, float* __restrict__ XK,
                                                    float* __restrict__ XV,
                                                    const float* __restrict__ lnw_g,
                                                    const float* __restrict__ lnb_g) {
    int g = blockIdx.x * 4 + (threadIdx.x >> 6); // (b*L+l)*H + h
    int d = threadIdx.x & 63;
    int h = g & (Hh - 1);
    size_t base = (size_t)(g >> 5) * Dd + h * 64 + d;
    float q = XQ[base], k = XK[base], v = XV[base];
    float nq = sqrtf(wsum64(q * q)); q /= fmaxf(nq, 1e-12f);
    float nk = sqrtf(wsum64(k * k)); k /= fmaxf(nk, 1e-12f);
    float diff = v - k;
    float mu = wsum64(diff) * (1.f / 64.f);
    float cc = diff - mu;
    float var = wsum64(cc * cc) * (1.f / 63.f); // ddof=1
    float vn = lnw_g[h * 64 + d] * cc / (sqrtf(var) + 1e-8f) + lnb_g[h * 64 + d] + k;
    XQ[base] = q; XK[base] = k; XV[base] = vn;
}

// ---------------- lr: s[b,h,l] = sigmoid(hs[b,l,:]·lr_w[h,:] + lr_b[h]) / (HD*K) ----------------
__global__ __launch_bounds__(256) void lr_kernel(const float* __restrict__ hs,
                                                 const float* __restrict__ lrw,
                                                 const float* __restrict__ lrb,
                                                 float* __restrict__ lr_out) {
    int tok = blockIdx.x; // b*L + l
    int t = threadIdx.x;
    int h = t >> 3, j0 = t & 7;
    const float* row = hs + (size_t)tok * Dd;
    const float* wr = lrw + (size_t)h * Dd;
    float p = 0.f;
    for (int j = j0 * 4; j < Dd; j += 32) {
        float4 a = *(const float4*)(row + j);
        float4 w = *(const float4*)(wr + j);
        p += a.x * w.x + a.y * w.y + a.z * w.z + a.w * w.w;
    }
    __shared__ float red[32][8];
    red[h][j0] = p;
    __syncthreads();
    if (t < 32) {
        float s = 0.f;
        #pragma unroll
        for (int i = 0; i < 8; ++i) s += red[t][i];
        s += lrb[t];
        s = 1.f / (1.f + expf(-s));
        s *= 1.0f / (HD * MBK);
        int b = tok >> 12, l = tok & (Ls - 1);
        lr_out[(size_t)(b * Hh + t) * Ls + l] = s;
    }
}

// ---------------- MFMA TTT scan: 4 waves per (b,h) chain ----------------
// Wave w owns output-column slab S_w = [16w, 16w+16). All operands LDS-resident.
// mfma_f32_16x16x32_bf16 layouts:
//   A-frag lane(q,n): A[m=n][k=8q+j]   B-frag: B[k=8q+j][n]   C: C[4q+r][n]
// W1 resident as bf16 hi+lo, transposed wt[col][k] (direct b128 B-frag reads).
// grad/sxk/att stored K=32 zero-padded -> unmasked K=32 frags for small MFMAs.
__global__ __launch_bounds__(256, 1) void scan_kernel(const float* __restrict__ XQ,
                                                      const float* __restrict__ XK,
                                                      const float* __restrict__ XV,
                                                      const float* __restrict__ lrbuf,
                                                      const float* __restrict__ W1in,
                                                      const float* __restrict__ b1in,
                                                      const float* __restrict__ lnw_g,
                                                      const float* __restrict__ lnb_g,
                                                      float* __restrict__ Y) {
    int bh = blockIdx.x;          // b*H + h
    int b = bh >> 5, h = bh & 31;
    int t = threadIdx.x;
    int w = t >> 6;               // wave 0..3
    int lane = t & 63;
    int q = lane >> 4, n = lane & 15;
    int gc = 16 * w + n;          // this lane's C-layout global column

    __shared__ float tiles[2][3][16 * 68];     // [buf][xq,xk,xv][token][feat]
    __shared__ float svb[2][16];
    __shared__ unsigned short wt_hi[64 * 72];  // [col][k]
    __shared__ unsigned short wt_lo[64 * 72];
    __shared__ float zT[64 * 20];              // [col][token] shared z1 / zbar bounce
    __shared__ unsigned short gbufT[64 * 32];  // [col][k] bf16, k>=16 zero
    __shared__ unsigned short sxkT[64 * 32];   // [col][k] bf16, k>=16 zero
    __shared__ float att32[16 * 32];           // [i][j] fp32, j>=16 zero
    __shared__ float pb[4 * 64];               // b1-partials [wave][col]

    // ---- init W1 as hi/lo bf16, transposed ----
    #pragma unroll
    for (int i = 0; i < 16; ++i) {
        int k = i * 4 + w;        // 0..63
        float val = W1in[(size_t)h * 4096 + (size_t)k * 64 + lane];
        unsigned short hi = f2bf(val);
        unsigned short lo = f2bf(val - b2f(hi));
        wt_hi[lane * 72 + k] = hi;
        wt_lo[lane * 72 + k] = lo;
    }
    // ---- zero pads ----
    #pragma unroll
    for (int i = 0; i < 8; ++i) { gbufT[i * 256 + t] = 0; sxkT[i * 256 + t] = 0; }
    #pragma unroll
    for (int i = 0; i < 2; ++i) att32[i * 256 + t] = 0.f;

    float b1r = b1in[h * 64 + lane];
    float lnwr = lnw_g[h * 64 + lane];
    float lnbr = lnb_g[h * 64 + lane];

    const size_t gbase = ((size_t)b * Ls) * Dd + h * 64;
    const float* lrp = lrbuf + (size_t)bh * Ls;

    int rowp = t >> 4, c4p = (t & 15) * 4;     // staging pattern: 16 rows x 16 float4
    // ---- prologue: step 0 direct to LDS, prefetch step 1 ----
    *(float4*)&tiles[0][0][rowp * 68 + c4p] = *(const float4*)(XQ + gbase + (size_t)rowp * Dd + c4p);
    *(float4*)&tiles[0][1][rowp * 68 + c4p] = *(const float4*)(XK + gbase + (size_t)rowp * Dd + c4p);
    *(float4*)&tiles[0][2][rowp * 68 + c4p] = *(const float4*)(XV + gbase + (size_t)rowp * Dd + c4p);
    if (t < 16) svb[0][t] = lrp[t];
    float4 preq = *(const float4*)(XQ + gbase + (size_t)(16 + rowp) * Dd + c4p);
    float4 prek = *(const float4*)(XK + gbase + (size_t)(16 + rowp) * Dd + c4p);
    float4 prev = *(const float4*)(XV + gbase + (size_t)(16 + rowp) * Dd + c4p);
    float presv = (t < 16) ? lrp[16 + t] : 0.f;
    __syncthreads();

    const f32x4 zero4 = {0.f, 0.f, 0.f, 0.f};

    for (int nmb = 0; nmb < NMBc; ++nmb) {
        int cb = nmb & 1, nb2 = cb ^ 1;
        int l0 = nmb * 16;
        // ---- stage step n+1 (from prefetch regs), issue prefetch n+2 ----
        *(float4*)&tiles[nb2][0][rowp * 68 + c4p] = preq;
        *(float4*)&tiles[nb2][1][rowp * 68 + c4p] = prek;
        *(float4*)&tiles[nb2][2][rowp * 68 + c4p] = prev;
        if (t < 16) svb[nb2][t] = presv;
        int lp = (l0 + 32 <= Ls - 16) ? (l0 + 32) : (Ls - 16);
        preq = *(const float4*)(XQ + gbase + (size_t)(lp + rowp) * Dd + c4p);
        prek = *(const float4*)(XK + gbase + (size_t)(lp + rowp) * Dd + c4p);
        prev = *(const float4*)(XV + gbase + (size_t)(lp + rowp) * Dd + c4p);
        presv = (t < 16) ? lrp[lp + t] : 0.f;

        const float* xqs = &tiles[cb][0][0];
        const float* xks = &tiles[cb][1][0];
        const float* xvs = &tiles[cb][2][0];

        // ---- build xq/xk A-frags (token n, feats 8q+j / 32+8q+j) ----
        bf16x8 qf0, qf1, kf0, kf1;
        {
            float4 a0 = *(const float4*)&xqs[n * 68 + 8 * q];
            float4 a1 = *(const float4*)&xqs[n * 68 + 8 * q + 4];
            float4 a2 = *(const float4*)&xqs[n * 68 + 32 + 8 * q];
            float4 a3 = *(const float4*)&xqs[n * 68 + 32 + 8 * q + 4];
            qf0[0]=(__bf16)a0.x; qf0[1]=(__bf16)a0.y; qf0[2]=(__bf16)a0.z; qf0[3]=(__bf16)a0.w;
            qf0[4]=(__bf16)a1.x; qf0[5]=(__bf16)a1.y; qf0[6]=(__bf16)a1.z; qf0[7]=(__bf16)a1.w;
            qf1[0]=(__bf16)a2.x; qf1[1]=(__bf16)a2.y; qf1[2]=(__bf16)a2.z; qf1[3]=(__bf16)a2.w;
            qf1[4]=(__bf16)a3.x; qf1[5]=(__bf16)a3.y; qf1[6]=(__bf16)a3.z; qf1[7]=(__bf16)a3.w;
            float4 k0 = *(const float4*)&xks[n * 68 + 8 * q];
            float4 k1 = *(const float4*)&xks[n * 68 + 8 * q + 4];
            float4 k2 = *(const float4*)&xks[n * 68 + 32 + 8 * q];
            float4 k3 = *(const float4*)&xks[n * 68 + 32 + 8 * q + 4];
            kf0[0]=(__bf16)k0.x; kf0[1]=(__bf16)k0.y; kf0[2]=(__bf16)k0.z; kf0[3]=(__bf16)k0.w;
            kf0[4]=(__bf16)k1.x; kf0[5]=(__bf16)k1.y; kf0[6]=(__bf16)k1.z; kf0[7]=(__bf16)k1.w;
            kf1[0]=(__bf16)k2.x; kf1[1]=(__bf16)k2.y; kf1[2]=(__bf16)k2.z; kf1[3]=(__bf16)k2.w;
            kf1[4]=(__bf16)k3.x; kf1[5]=(__bf16)k3.y; kf1[6]=(__bf16)k3.z; kf1[7]=(__bf16)k3.w;
        }
        // ---- W1 B-frags (own slab) ----
        bf16x8 wh0 = *(const bf16x8*)&wt_hi[gc * 72 + 8 * q];
        bf16x8 wh1 = *(const bf16x8*)&wt_hi[gc * 72 + 32 + 8 * q];
        bf16x8 wl0 = *(const bf16x8*)&wt_lo[gc * 72 + 8 * q];
        bf16x8 wl1 = *(const bf16x8*)&wt_lo[gc * 72 + 32 + 8 * q];

        // ---- MFMAs: Attn (redundant per wave), Z1 slab, Zbar partial ----
        f32x4 aacc = __builtin_amdgcn_mfma_f32_16x16x32_bf16(qf1, kf1, zero4, 0, 0, 0);
        aacc = __builtin_amdgcn_mfma_f32_16x16x32_bf16(qf0, kf0, aacc, 0, 0, 0);
        f32x4 z1 = __builtin_amdgcn_mfma_f32_16x16x32_bf16(kf0, wh0, zero4, 0, 0, 0);
        z1 = __builtin_amdgcn_mfma_f32_16x16x32_bf16(kf1, wh1, z1, 0, 0, 0);
        z1 = __builtin_amdgcn_mfma_f32_16x16x32_bf16(kf0, wl0, z1, 0, 0, 0);
        z1 = __builtin_amdgcn_mfma_f32_16x16x32_bf16(kf1, wl1, z1, 0, 0, 0);
        f32x4 zb = __builtin_amdgcn_mfma_f32_16x16x32_bf16(qf0, wh0, zero4, 0, 0, 0);
        zb = __builtin_amdgcn_mfma_f32_16x16x32_bf16(qf1, wh1, zb, 0, 0, 0);
        zb = __builtin_amdgcn_mfma_f32_16x16x32_bf16(qf0, wl0, zb, 0, 0, 0);
        zb = __builtin_amdgcn_mfma_f32_16x16x32_bf16(qf1, wl1, zb, 0, 0, 0);

        // ---- bounce Z1 (transposed) ----
        {
            float4 zs; zs.x = z1[0]; zs.y = z1[1]; zs.z = z1[2]; zs.w = z1[3];
            *(float4*)&zT[gc * 20 + 4 * q] = zs;
        }
        // ---- masked -sv_j*(Attn+1) (wave 0 writes) ----
        if (w == 0) {
            float svn = svb[cb][n];
            #pragma unroll
            for (int r = 0; r < 4; ++r) {
                int i = 4 * q + r;
                att32[i * 32 + n] = (i >= n) ? (-svn * (aacc[r] + 1.f)) : 0.f;
            }
        }
        __syncthreads(); // B1

        // ======== row-major grad phase: lane = col, rows 4w+r ========
        float4 zz = *(const float4*)&zT[lane * 20 + 4 * w];
        float zar[4] = {zz.x + b1r, zz.y + b1r, zz.z + b1r, zz.w + b1r};
        float xk_rm[4], xv_rm[4], xq_rm[4];
        #pragma unroll
        for (int r = 0; r < 4; ++r) {
            int rw = 4 * w + r;
            xk_rm[r] = xks[rw * 68 + lane];
            xv_rm[r] = xvs[rw * 68 + lane];
            xq_rm[r] = xqs[rw * 68 + lane];
        }
        float4 svr4 = *(const float4*)&svb[cb][4 * w];
        float svr[4] = {svr4.x, svr4.y, svr4.z, svr4.w};
        float gr[4]; float pbv = 0.f;
        #pragma unroll
        for (int r = 0; r < 4; ++r) {
            float s1 = wsum64(zar[r]);
            float s2 = wsum64(zar[r] * zar[r]);
            float mu = s1 * (1.f / 64.f);
            float var = s2 * (1.f / 64.f) - mu * mu;
            float rstd = rsqrtf(var + 1e-6f);
            float xh = (zar[r] - mu) * rstd;
            float g = (lnwr * xh + lnbr - (xv_rm[r] - xk_rm[r])) * lnwr;
            float sg = wsum64(g);
            float sxg = wsum64(xh * g);
            gr[r] = (64.f * g - sg - xh * sxg) * rstd * (1.f / 64.f);
            pbv += svr[r] * gr[r];
        }
        {
            ushort4 gp, sp;
            gp.x = f2bf(gr[0]); gp.y = f2bf(gr[1]); gp.z = f2bf(gr[2]); gp.w = f2bf(gr[3]);
            sp.x = f2bf(svr[0] * xk_rm[0]); sp.y = f2bf(svr[1] * xk_rm[1]);
            sp.z = f2bf(svr[2] * xk_rm[2]); sp.w = f2bf(svr[3] * xk_rm[3]);
            *(ushort4*)&gbufT[lane * 32 + 4 * w] = gp;
            *(ushort4*)&sxkT[lane * 32 + 4 * w] = sp;
            pb[w * 64 + lane] = pbv;
        }
        __syncthreads(); // B2

        // ---- grad B-frag (own slab), masked-attn A-frag (K=32, zero-padded) ----
        bf16x8 gF = *(const bf16x8*)&gbufT[gc * 32 + 8 * q];
        bf16x8 amF;
        {
            float4 f0 = *(const float4*)&att32[n * 32 + 8 * q];
            float4 f1 = *(const float4*)&att32[n * 32 + 8 * q + 4];
            amF[0]=(__bf16)f0.x; amF[1]=(__bf16)f0.y; amF[2]=(__bf16)f0.z; amF[3]=(__bf16)f0.w;
            amF[4]=(__bf16)f1.x; amF[5]=(__bf16)f1.y; amF[6]=(__bf16)f1.z; amF[7]=(__bf16)f1.w;
        }
        // ---- finish Zbar, bounce transposed ----
        zb = __builtin_amdgcn_mfma_f32_16x16x32_bf16(amF, gF, zb, 0, 0, 0);
        {
            float4 zs; zs.x = zb[0]; zs.y = zb[1]; zs.z = zb[2]; zs.w = zb[3];
            *(float4*)&zT[gc * 20 + 4 * q] = zs;
        }
        // ---- W1 update: own slab -= (sv.xk)^T @ grad ----
        #pragma unroll
        for (int tm = 0; tm < 4; ++tm) {
            bf16x8 ax = *(const bf16x8*)&sxkT[(16 * tm + n) * 32 + 8 * q];
            f32x4 dl = __builtin_amdgcn_mfma_f32_16x16x32_bf16(ax, gF, zero4, 0, 0, 0);
            int ko = 16 * tm + 4 * q;
            ushort4 h4 = *(ushort4*)&wt_hi[gc * 72 + ko];
            ushort4 l4 = *(ushort4*)&wt_lo[gc * 72 + ko];
            float w0 = b2f(h4.x) + b2f(l4.x) - dl[0];
            float w1 = b2f(h4.y) + b2f(l4.y) - dl[1];
            float w2 = b2f(h4.z) + b2f(l4.z) - dl[2];
            float w3 = b2f(h4.w) + b2f(l4.w) - dl[3];
            h4.x = f2bf(w0); l4.x = f2bf(w0 - b2f(h4.x));
            h4.y = f2bf(w1); l4.y = f2bf(w1 - b2f(h4.y));
            h4.z = f2bf(w2); l4.z = f2bf(w2 - b2f(h4.z));
            h4.w = f2bf(w3); l4.w = f2bf(w3 - b2f(h4.w));
            *(ushort4*)&wt_hi[gc * 72 + ko] = h4;
            *(ushort4*)&wt_lo[gc * 72 + ko] = l4;
        }
        // ---- b1 update (uses old b1r after B3) ----
        float b1n_ = b1r - (pb[0 * 64 + lane] + pb[1 * 64 + lane] +
                            pb[2 * 64 + lane] + pb[3 * 64 + lane]);
        __syncthreads(); // B3

        // ======== row-major Zbar LN + output ========
        float4 zz2 = *(const float4*)&zT[lane * 20 + 4 * w];
        float zbr[4] = {zz2.x + b1r, zz2.y + b1r, zz2.z + b1r, zz2.w + b1r};
        #pragma unroll
        for (int r = 0; r < 4; ++r) {
            float s1 = wsum64(zbr[r]);
            float s2 = wsum64(zbr[r] * zbr[r]);
            float mu = s1 * (1.f / 64.f);
            float var = s2 * (1.f / 64.f) - mu * mu;
            float rstd = rsqrtf(var + 1e-6f);
            float o = lnwr * ((zbr[r] - mu) * rstd) + lnbr + xq_rm[r];
            Y[gbase + (size_t)(l0 + 4 * w + r) * Dd + lane] = o;
        }
        b1r = b1n_;
        __syncthreads(); // B4 (protects zT + tile-buffer reuse)
    }
}

// ---------------- post layernorm over D + cast to bf16 ----------------
__global__ __launch_bounds__(256) void postnorm_kernel(const float* __restrict__ Y,
                                                       const float* __restrict__ pw,
                                                       const float* __restrict__ pb,
                                                       unsigned short* __restrict__ Yb) {
    int tok = blockIdx.x, t = threadIdx.x;
    const float* row = Y + (size_t)tok * Dd;
    int c0 = t * 4, c1 = 1024 + t * 4;
    float4 v0 = *(const float4*)(row + c0);
    float4 v1 = *(const float4*)(row + c1);
    float s1 = v0.x + v0.y + v0.z + v0.w + v1.x + v1.y + v1.z + v1.w;
    float s2 = v0.x * v0.x + v0.y * v0.y + v0.z * v0.z + v0.w * v0.w +
               v1.x * v1.x + v1.y * v1.y + v1.z * v1.z + v1.w * v1.w;
    s1 = wsum64(s1); s2 = wsum64(s2);
    __shared__ float r1[4], r2[4];
    if ((t & 63) == 0) { r1[t >> 6] = s1; r2[t >> 6] = s2; }
    __syncthreads();
    float S1 = r1[0] + r1[1] + r1[2] + r1[3];
    float S2 = r2[0] + r2[1] + r2[2] + r2[3];
    float mu = S1 * (1.f / 2048.f);
    float var = S2 * (1.f / 2048.f) - mu * mu;
    float rstd = rsqrtf(var + 1e-6f);
    float4 w0 = *(const float4*)(pw + c0), b0 = *(const float4*)(pb + c0);
    float4 w1 = *(const float4*)(pw + c1), b1 = *(const float4*)(pb + c1);
    ushort4 o0, o1;
    o0.x = f2bf((v0.x - mu) * rstd * w0.x + b0.x);
    o0.y = f2bf((v0.y - mu) * rstd * w0.y + b0.y);
    o0.z = f2bf((v0.z - mu) * rstd * w0.z + b0.z);
    o0.w = f2bf((v0.w - mu) * rstd * w0.w + b0.w);
    o1.x = f2bf((v1.x - mu) * rstd * w1.x + b1.x);
    o1.y = f2bf((v1.y - mu) * rstd * w1.y + b1.y);
    o1.z = f2bf((v1.z - mu) * rstd * w1.z + b1.z);
    o1.w = f2bf((v1.w - mu) * rstd * w1.w + b1.w);
    *(ushort4*)(Yb + (size_t)tok * Dd + c0) = o0;
    *(ushort4*)(Yb + (size_t)tok * Dd + c1) = o1;
}

extern "C" void kernel_launch(void* const* d_in, const int* in_sizes, int n_in,
                              void* d_out, int out_size, void* d_ws, size_t ws_size,
                              hipStream_t stream) {
    const float* hs   = (const float*)d_in[0];
    const float* wq_w = (const float*)d_in[1];
    const float* wq_b = (const float*)d_in[2];
    const float* wk_w = (const float*)d_in[3];
    const float* wk_b = (const float*)d_in[4];
    const float* wv_w = (const float*)d_in[5];
    const float* wv_b = (const float*)d_in[6];
    const float* wo_w = (const float*)d_in[7];
    const float* wo_b = (const float*)d_in[8];
    const float* lnw  = (const float*)d_in[9];
    const float* lnb  = (const float*)d_in[10];
    const float* lr_w = (const float*)d_in[11];
    const float* lr_b = (const float*)d_in[12];
    const float* W1   = (const float*)d_in[13];
    const float* b1   = (const float*)d_in[14];
    const float* pnw  = (const float*)d_in[15];
    const float* pnb  = (const float*)d_in[16];
    float* out = (float*)d_out;

    char* ws = (char*)d_ws;
    size_t off = 0;
    auto alloc = [&](size_t bytes) -> void* {
        void* p = ws + off; off += (bytes + 255) & ~(size_t)255; return p;
    };
    unsigned short* hsb = (unsigned short*)alloc((size_t)MTOK * Dd * 2);
    unsigned short* wtb = (unsigned short*)alloc((size_t)Dd * Dd * 2);
    float* XQ = (float*)alloc((size_t)MTOK * Dd * 4);
    float* XK = (float*)alloc((size_t)MTOK * Dd * 4);
    float* XV = (float*)alloc((size_t)MTOK * Dd * 4);
    float* lrbuf = (float*)alloc((size_t)Bb * Hh * Ls * 4);
    float* Y = XQ;                 // safe alias (per-chain row/col ownership; writes trail reads)
    unsigned short* Yb = hsb;      // hsb dead after QKV GEMMs

    dim3 blk(256);
    cast_hs_kernel<<<dim3(MTOK * Dd / 1024), blk, 0, stream>>>(hs, hsb);

    transpose_cast_kernel<<<dim3(1024), blk, 0, stream>>>(wq_w, wtb);
    gemm_bt_kernel<<<dim3(64, 16), blk, 0, stream>>>(hsb, wtb, wq_b, XQ, MTOK, Dd, Dd);
    transpose_cast_kernel<<<dim3(1024), blk, 0, stream>>>(wk_w, wtb);
    gemm_bt_kernel<<<dim3(64, 16), blk, 0, stream>>>(hsb, wtb, wk_b, XK, MTOK, Dd, Dd);
    transpose_cast_kernel<<<dim3(1024), blk, 0, stream>>>(wv_w, wtb);
    gemm_bt_kernel<<<dim3(64, 16), blk, 0, stream>>>(hsb, wtb, wv_b, XV, MTOK, Dd, Dd);

    fixup_kernel<<<dim3(Bb * Ls * Hh / 4), blk, 0, stream>>>(XQ, XK, XV, lnw, lnb);
    lr_kernel<<<dim3(MTOK), blk, 0, stream>>>(hs, lr_w, lr_b, lrbuf);

    scan_kernel<<<dim3(Bb * Hh), blk, 0, stream>>>(XQ, XK, XV, lrbuf, W1, b1, lnw, lnb, Y);

    postnorm_kernel<<<dim3(MTOK), blk, 0, stream>>>(Y, pnw, pnb, Yb);

    transpose_cast_kernel<<<dim3(1024), blk, 0, stream>>>(wo_w, wtb);
    gemm_bt_kernel<<<dim3(64, 16), blk, 0, stream>>>(Yb, wtb, wo_b, out, MTOK, Dd, Dd);
}